// Round 5
// baseline (279.542 us; speedup 1.0000x reference)
//
#include <hip/hip_runtime.h>

// Weighted keypoint MSE loss:
//   oob = (tx<0)|(tx>1024)|(ty<0)|(ty>1024)
//   loss = sum( (oob ? 0.01 : 1.0) * ((ox-tx)^2 + (oy-ty)^2) ) / B
// Inputs: output [B,K,2] fp32, target [B,K,2] fp32, B=4096, K=4096. 268 MB read.
//
// R1: scalar-ish loop, 2 loads in flight -> 104 us latency-bound (2.6 TB/s app).
// R2/R3: manual unroll + fences -> compiler re-serialized both times (VGPR 28/32).
// R4: inline-asm waitcnt with tied float4 operands -> doesn't compile.
// R5: global_load_lds DMA queue. In-flight data costs ZERO VGPRs, so the
//     register-pressure heuristic can't serialize it. Per-wave private LDS
//     slices, bulk-synchronous: issue 16 DMAs (16 KB), vmcnt(0), consume from
//     LDS. No __syncthreads needed (no cross-wave sharing). 2 blocks/CU
//     alternate drain/consume -> HBM stays busy.

#define WIDTH_F  1024.0f
#define HEIGHT_F 1024.0f
#define OOB_W    0.01f
#define SLOTS    8   // stages per batch; per-wave LDS slice = SLOTS*2 KB = 16 KB

typedef const __attribute__((address_space(1))) void* gptr_t;
typedef __attribute__((address_space(3))) void*       lptr_t;

__device__ __forceinline__ float kp_pair(float4 o, float4 t) {
    float dx = o.x - t.x;
    float dy = o.y - t.y;
    float sqA = dx * dx + dy * dy;
    bool oobA = (t.x < 0.0f) || (t.x > WIDTH_F) || (t.y < 0.0f) || (t.y > HEIGHT_F);
    float dz = o.z - t.z;
    float dw = o.w - t.w;
    float sqB = dz * dz + dw * dw;
    bool oobB = (t.z < 0.0f) || (t.z > WIDTH_F) || (t.w < 0.0f) || (t.w > HEIGHT_F);
    return (oobA ? OOB_W : 1.0f) * sqA + (oobB ? OOB_W : 1.0f) * sqB;
}

__global__ __launch_bounds__(256) void res_kp_loss_kernel(
    const float4* __restrict__ out4,
    const float4* __restrict__ tgt4,
    float* __restrict__ result,
    int n4,
    float inv_b) {
    // Per-wave slice: SLOTS slots, each 128 float4 = [0..63]=o, [64..127]=t.
    // lane's DMA dest = wave-uniform slot base + lane*16B  (m104 constraint OK).
    __shared__ float4 lds[4][SLOTS][128];  // 64 KB

    const int tid    = threadIdx.x;
    const int wave   = tid >> 6;
    const int lane   = tid & 63;
    const int idx    = blockIdx.x * blockDim.x + tid;
    const int stride = gridDim.x * blockDim.x;

    const int nstages = n4 / stride;        // 16 at bench shape
    const int nbatch  = nstages / SLOTS;    // 2 at bench shape

    float acc = 0.0f;

    for (int b = 0; b < nbatch; ++b) {
        const int base = b * SLOTS;
        // Issue 16 direct-to-LDS DMAs back-to-back: 16 KB in flight per wave,
        // zero VGPRs held.
        #pragma unroll
        for (int s = 0; s < SLOTS; ++s) {
            const long gi = (long)(base + s) * stride + idx;
            __builtin_amdgcn_global_load_lds((gptr_t)(out4 + gi),
                                             (lptr_t)&lds[wave][s][lane],
                                             16, 0, 0);
            __builtin_amdgcn_global_load_lds((gptr_t)(tgt4 + gi),
                                             (lptr_t)&lds[wave][s][64 + lane],
                                             16, 0, 0);
        }
        // Drain the DMA queue: vmcnt(0), lgkm/exp don't-care (0xF70).
        __builtin_amdgcn_s_waitcnt(0x0F70);
        // Consume from our own LDS slice (ds_read_b128; no barrier needed).
        #pragma unroll
        for (int s = 0; s < SLOTS; ++s)
            acc += kp_pair(lds[wave][s][lane], lds[wave][s][64 + lane]);
    }

    // Ragged stages beyond full batches (none at bench shape).
    for (int s = nbatch * SLOTS; s < nstages; ++s) {
        const long gi = (long)s * stride + idx;
        acc += kp_pair(out4[gi], tgt4[gi]);
    }
    // Remainder elements if n4 % stride != 0 (none at bench shape).
    for (long i = (long)nstages * stride + idx; i < n4; i += stride)
        acc += kp_pair(out4[i], tgt4[i]);

    // wave-64 shuffle reduction
    #pragma unroll
    for (int off = 32; off > 0; off >>= 1)
        acc += __shfl_down(acc, off, 64);

    __shared__ float wave_sums[4];
    if (lane == 0) wave_sums[wave] = acc;
    __syncthreads();

    if (tid == 0) {
        float s = (wave_sums[0] + wave_sums[1]) + (wave_sums[2] + wave_sums[3]);
        atomicAdd(result, s * inv_b);  // device-scope by default on CDNA
    }
}

extern "C" void kernel_launch(void* const* d_in, const int* in_sizes, int n_in,
                              void* d_out, int out_size, void* d_ws, size_t ws_size,
                              hipStream_t stream) {
    const float4* out4 = (const float4*)d_in[0];  // output [B,K,2] fp32
    const float4* tgt4 = (const float4*)d_in[1];  // target [B,K,2] fp32
    float* result = (float*)d_out;

    const int total_floats = in_sizes[0];          // B*K*2 = 33,554,432
    const int n4 = total_floats / 4;               // 8,388,608 float4 per array
    const float inv_b = 1.0f / 4096.0f;            // B = 4096

    // d_out is poisoned 0xAA before every timed launch — zero it (async, capture-safe)
    (void)hipMemsetAsync(d_out, 0, out_size * sizeof(float), stream);

    const int block = 256;
    const int grid = 2048;  // 16 float4 per thread per array; 8192 waves total
    res_kp_loss_kernel<<<grid, block, 0, stream>>>(out4, tgt4, result, n4, inv_b);
}

// Round 6
// 275.925 us; speedup vs baseline: 1.0131x; 1.0131x over previous
//
#include <hip/hip_runtime.h>

// Weighted keypoint MSE loss:
//   oob = (tx<0)|(tx>1024)|(ty<0)|(ty>1024)
//   loss = sum( (oob ? 0.01 : 1.0) * ((ox-tx)^2 + (oy-ty)^2) ) / B
// Inputs: output [B,K,2] fp32, target [B,K,2] fp32, B=4096, K=4096. 268 MB read.
//
// History:
//   R1 grid-stride float4 loop + 2048 same-address atomicAdds  -> 104 us
//   R2/R3 manual unroll / fences (compiler re-serialized)      -> 102-104 us
//   R5 global_load_lds 16-deep DMA queue, 2 blocks/CU          -> 126 us
// Three different load structures, same ~2.6 TB/s -> load-side MLP is NOT the
// limiter. Common factor: 2048 fire-and-forget atomicAdds to ONE address,
// serialized memory-side across 8 non-coherent XCDs AFTER waves retire.
// R6: zero atomics. Block partials -> d_ws (plain stores), tiny second kernel
// reduces 2048 floats. Load loop byte-identical to R1 to isolate the change.

#define WIDTH_F  1024.0f
#define HEIGHT_F 1024.0f
#define OOB_W    0.01f

__device__ __forceinline__ float kp_pair(float4 o, float4 t) {
    float dx = o.x - t.x;
    float dy = o.y - t.y;
    float sqA = dx * dx + dy * dy;
    bool oobA = (t.x < 0.0f) || (t.x > WIDTH_F) || (t.y < 0.0f) || (t.y > HEIGHT_F);
    float dz = o.z - t.z;
    float dw = o.w - t.w;
    float sqB = dz * dz + dw * dw;
    bool oobB = (t.z < 0.0f) || (t.z > WIDTH_F) || (t.w < 0.0f) || (t.w > HEIGHT_F);
    return (oobA ? OOB_W : 1.0f) * sqA + (oobB ? OOB_W : 1.0f) * sqB;
}

__global__ __launch_bounds__(256) void kp_main(
    const float4* __restrict__ out4,
    const float4* __restrict__ tgt4,
    float* __restrict__ partials,   // [gridDim.x] in d_ws
    int n4) {
    int idx    = blockIdx.x * blockDim.x + threadIdx.x;
    int stride = gridDim.x * blockDim.x;

    float acc = 0.0f;
    for (int i = idx; i < n4; i += stride) {
        float4 o = out4[i];
        float4 t = tgt4[i];
        acc += kp_pair(o, t);
    }

    // wave-64 shuffle reduction
    #pragma unroll
    for (int off = 32; off > 0; off >>= 1)
        acc += __shfl_down(acc, off, 64);

    __shared__ float wave_sums[4];
    int lane = threadIdx.x & 63;
    int wave = threadIdx.x >> 6;
    if (lane == 0) wave_sums[wave] = acc;
    __syncthreads();

    if (threadIdx.x == 0) {
        partials[blockIdx.x] =
            (wave_sums[0] + wave_sums[1]) + (wave_sums[2] + wave_sums[3]);
    }
}

__global__ __launch_bounds__(256) void kp_finalize(
    const float* __restrict__ partials,
    float* __restrict__ result,
    int nparts,
    float inv_b) {
    float acc = 0.0f;
    for (int i = threadIdx.x; i < nparts; i += 256)
        acc += partials[i];

    #pragma unroll
    for (int off = 32; off > 0; off >>= 1)
        acc += __shfl_down(acc, off, 64);

    __shared__ float wave_sums[4];
    int lane = threadIdx.x & 63;
    int wave = threadIdx.x >> 6;
    if (lane == 0) wave_sums[wave] = acc;
    __syncthreads();

    if (threadIdx.x == 0) {
        result[0] = ((wave_sums[0] + wave_sums[1]) +
                     (wave_sums[2] + wave_sums[3])) * inv_b;
    }
}

extern "C" void kernel_launch(void* const* d_in, const int* in_sizes, int n_in,
                              void* d_out, int out_size, void* d_ws, size_t ws_size,
                              hipStream_t stream) {
    const float4* out4 = (const float4*)d_in[0];  // output [B,K,2] fp32
    const float4* tgt4 = (const float4*)d_in[1];  // target [B,K,2] fp32
    float* result   = (float*)d_out;
    float* partials = (float*)d_ws;               // 2048 * 4 B = 8 KB scratch

    const int total_floats = in_sizes[0];          // B*K*2 = 33,554,432
    const int n4 = total_floats / 4;               // 8,388,608 float4 per array
    const float inv_b = 1.0f / 4096.0f;            // B = 4096

    const int block = 256;
    const int grid = 2048;  // 16 float4 per thread per array; every slot written

    kp_main<<<grid, block, 0, stream>>>(out4, tgt4, partials, n4);
    kp_finalize<<<1, block, 0, stream>>>(partials, result, grid, inv_b);
}